// Round 1
// 230.329 us; speedup vs baseline: 1.0803x; 1.0803x over previous
//
#include <hip/hip_runtime.h>
#include <math.h>

#define D 64
#define K 4096
// Round-9: fp16 two-product scheme. Error budget: e quantized to fp16
// (rel 2^-11), z carried to ~2^-22 via hi/lo fp16 split. sigma(dq) ~ 5e-3,
// worst realistic contender-pair delta ~0.04 -> MARGIN 0.08 (~2x headroom).
#define MARGIN 0.08f
#define KSPLIT 4
#define CPH (K / 16 / KSPLIT)  // chunks of 16 codes per half = 64

typedef float f32x4 __attribute__((ext_vector_type(4)));
typedef _Float16 f16x8 __attribute__((ext_vector_type(8)));

// ---------------------------------------------------------------------------
// e_sq[k] = sum_d emb[k][d]^2  (exact fp32)
// ---------------------------------------------------------------------------
__global__ __launch_bounds__(256) void esq_kernel(const float* __restrict__ emb,
                                                  float* __restrict__ e_sq) {
  int k = blockIdx.x * 256 + threadIdx.x;
  if (k >= K) return;
  const float* e = emb + (size_t)k * D;
  float s = 0.f;
#pragma unroll
  for (int d = 0; d < D; ++d) s = fmaf(e[d], e[d], s);
  e_sq[k] = s;
}

// ---------------------------------------------------------------------------
// Round-9: single fp16 copy of emb (RNE), PRE-SWIZZLED into MFMA B-fragment
// order: element (code k=c*16+col, dim d=t*32+quad*8+j) ->
// ((c*2+t)*64 + quad*16+col)*8 + j. Each B-frag read in dist_kernel is one
// fully-coalesced 1KB wave load. e_lo is GONE (the dropped hi*lo / lo*lo
// products are covered by the widened MARGIN + exact resolve).
// ---------------------------------------------------------------------------
__global__ __launch_bounds__(256) void esplit_kernel(const float* __restrict__ emb,
                                                     short* __restrict__ e_h) {
  int i = blockIdx.x * 256 + threadIdx.x;  // [0, 256*2*64)
  if (i >= (K / 16) * 2 * 64) return;
  int lane = i & 63;
  int t = (i >> 6) & 1;
  int c = i >> 7;
  int quad = lane >> 4, col = lane & 15;
  const float* src = emb + (size_t)(c * 16 + col) * D + t * 32 + quad * 8;
  f32x4 u0 = *(const f32x4*)src;
  f32x4 u1 = *(const f32x4*)(src + 4);
  f16x8 h;
#pragma unroll
  for (int j = 0; j < 8; ++j) {
    float x = (j < 4) ? u0[j] : u1[j - 4];
    h[j] = (_Float16)x;
  }
  *(f16x8*)(e_h + (size_t)i * 8) = h;
}

// ---------------------------------------------------------------------------
// Barrier-free MFMA dist/argmin, round-9 structure:
//  * fp16 2-product: (zh + zl) * eh  -> 8 MFMA/chunk (was 12), 2 B-loads/chunk
//    (was 4), half the L2 B traffic. Round-8 diagnosis: ~50% of dist was
//    load-latency stall (MfmaUtil 34 + trueVALU ~22 -> 50% idle).
//  * depth-1 software prefetch of next chunk's B frags + esq (the VGPR=48
//    build had no pipelining). +9 regs, still < 128 -> no spill risk; wave
//    state stays far below the ~120-reg AGPR-spill cliff from round-8.
//  * esq folded into the acc seed (-esq/2); track MAX of acc (== min of q);
//    convert back to q-space before the column merge so pbest/psec formats
//    and merge/resolve stay byte-identical to the field-tested versions.
// A[m=lane&15][k=quad*8+j]; B[n=lane&15][k=quad*8+j]; C/D row=quad*4+r, col=lane&15.
// ---------------------------------------------------------------------------
__global__ __launch_bounds__(256, 2) void dist_kernel(const float* __restrict__ z_e,
                                                      const short* __restrict__ e_h,
                                                      const float* __restrict__ esq,
                                                      float* __restrict__ pbest,
                                                      float* __restrict__ psec,
                                                      int* __restrict__ pidx) {
  const int tid = threadIdx.x;
  const int wv = tid >> 6;
  const int lane = tid & 63;
  const int quad = lane >> 4, col = lane & 15;
  const int rowbase = blockIdx.x * 128 + wv * 32;
  const int half = blockIdx.y;
  const int c0 = half * CPH;

  // ---- A fragments: 2 m-tiles x 2 k-halves, z split to fp16 hi/lo ----
  f16x8 a_hi[2][2], a_lo[2][2];
#pragma unroll
  for (int s = 0; s < 2; ++s) {
#pragma unroll
    for (int t = 0; t < 2; ++t) {
      const float* zr = z_e + (size_t)(rowbase + s * 16 + col) * D + t * 32 + quad * 8;
      f32x4 u0 = *(const f32x4*)zr;
      f32x4 u1 = *(const f32x4*)(zr + 4);
#pragma unroll
      for (int j = 0; j < 8; ++j) {
        float x = (j < 4) ? u0[j] : u1[j - 4];
        _Float16 h = (_Float16)x;
        a_hi[s][t][j] = h;
        a_lo[s][t][j] = (_Float16)(x - (float)h);
      }
    }
  }

  // Max-space tracking: acc = dot - esq/2, q = -2*acc. Larger acc == smaller q.
  float best[8], second[8];
  int bidx[8];
#pragma unroll
  for (int i = 0; i < 8; ++i) {
    best[i] = -__builtin_inff();
    second[i] = -__builtin_inff();
    bidx[i] = 0;
  }

  const short* pB = e_h + (size_t)c0 * 1024 + (size_t)lane * 8;
  const float* pE = esq + c0 * 16 + col;
  f16x8 b0 = *(const f16x8*)pB;
  f16x8 b1 = *(const f16x8*)(pB + 512);
  float eq = *pE;
  int code = c0 * 16 + col;

  for (int cc = 0; cc < CPH; ++cc) {
    // prefetch next chunk (last iter reads into the 4KB pad after e_h /
    // the head of e_h for esq -- in-workspace, values discarded)
    pB += 1024;
    pE += 16;
    f16x8 n0 = *(const f16x8*)pB;
    f16x8 n1 = *(const f16x8*)(pB + 512);
    float neq = *pE;

    const float seed = -0.5f * eq;
    f32x4 acc0 = {seed, seed, seed, seed};
    f32x4 acc1 = acc0;
    acc0 = __builtin_amdgcn_mfma_f32_16x16x32_f16(a_hi[0][0], b0, acc0, 0, 0, 0);
    acc1 = __builtin_amdgcn_mfma_f32_16x16x32_f16(a_hi[1][0], b0, acc1, 0, 0, 0);
    acc0 = __builtin_amdgcn_mfma_f32_16x16x32_f16(a_lo[0][0], b0, acc0, 0, 0, 0);
    acc1 = __builtin_amdgcn_mfma_f32_16x16x32_f16(a_lo[1][0], b0, acc1, 0, 0, 0);
    acc0 = __builtin_amdgcn_mfma_f32_16x16x32_f16(a_hi[0][1], b1, acc0, 0, 0, 0);
    acc1 = __builtin_amdgcn_mfma_f32_16x16x32_f16(a_hi[1][1], b1, acc1, 0, 0, 0);
    acc0 = __builtin_amdgcn_mfma_f32_16x16x32_f16(a_lo[0][1], b1, acc0, 0, 0, 0);
    acc1 = __builtin_amdgcn_mfma_f32_16x16x32_f16(a_lo[1][1], b1, acc1, 0, 0, 0);

#pragma unroll
    for (int r = 0; r < 4; ++r) {
      float q = acc0[r];
      float ob = best[r];
      best[r] = fmaxf(ob, q);
      second[r] = __builtin_amdgcn_fmed3f(ob, q, second[r]);
      bidx[r] = (q > ob) ? code : bidx[r];  // strict >: ties keep earlier (lower) code
    }
#pragma unroll
    for (int r = 0; r < 4; ++r) {
      float q = acc1[r];
      float ob = best[4 + r];
      best[4 + r] = fmaxf(ob, q);
      second[4 + r] = __builtin_amdgcn_fmed3f(ob, q, second[4 + r]);
      bidx[4 + r] = (q > ob) ? code : bidx[4 + r];
    }

    b0 = n0;
    b1 = n1;
    eq = neq;
    code += 16;
  }

  // ---- convert to q-space, merge across the 16 code-columns ----
#pragma unroll
  for (int i = 0; i < 8; ++i) {
    float b = -2.f * best[i];
    float s2 = -2.f * second[i];
    int ix = bidx[i];
#pragma unroll
    for (int off = 1; off < 16; off <<= 1) {
      float ob = __shfl_xor(b, off);
      float os = __shfl_xor(s2, off);
      int oi = __shfl_xor(ix, off);
      float ns = fminf(fminf(s2, os), fmaxf(b, ob));
      if (ob < b || (ob == b && oi < ix)) ix = oi;
      b = fminf(b, ob);
      s2 = ns;
    }
    if (col == 0) {
      int row = rowbase + (i >> 2) * 16 + quad * 4 + (i & 3);
      size_t o = (size_t)half * 65536 + row;
      pbest[o] = b;
      psec[o] = s2;
      pidx[o] = ix;
    }
  }
}

// ---------------------------------------------------------------------------
// Merge the KSPLIT partials per row; write best_idx; compact ambiguous rows
// (gap < MARGIN) into a worklist. Halves ascending, strict < -> first-occurrence.
// ---------------------------------------------------------------------------
__global__ __launch_bounds__(256) void merge_kernel(const float* __restrict__ pbest,
                                                    const float* __restrict__ psec,
                                                    const int* __restrict__ pidx,
                                                    int* __restrict__ best_idx,
                                                    int* __restrict__ worklist,
                                                    int* __restrict__ nwork,
                                                    int N) {
  int row = blockIdx.x * 256 + threadIdx.x;
  float b = pbest[row];
  float s2 = psec[row];
  int ix = pidx[row];
#pragma unroll
  for (int h = 1; h < KSPLIT; ++h) {
    size_t o = (size_t)h * 65536 + row;
    float bh = pbest[o];
    float sh = psec[o];
    int ih = pidx[o];
    s2 = fminf(fminf(s2, sh), fmaxf(b, bh));
    if (bh < b) ix = ih;  // strict <: ties keep lower-half (smaller) index
    b = fminf(b, bh);
  }
  best_idx[row] = ix;
  if (s2 - b < MARGIN) {
    int slot = atomicAdd(nwork, 1);
    worklist[slot] = row;
  }
}

// ---------------------------------------------------------------------------
// Candidate-based exact resolve (round-8, correctness field-tested). Per
// ambiguous row: a half with second_h < B+MARGIN may hide an unknown
// contender -> exact fp32 scan of that 1024-code half. A half with
// best_h < B+MARGIN <= second_h has exactly one candidate -> one 256B dot.
// Round-9: MARGIN widened to 0.08 (~2.4% of rows); grid bumped to 512 blocks.
// ---------------------------------------------------------------------------
__global__ __launch_bounds__(256, 1) void resolve_kernel(const float* __restrict__ z_e,
                                                         const float* __restrict__ emb,
                                                         const float* __restrict__ esq,
                                                         const float* __restrict__ pbest,
                                                         const float* __restrict__ psec,
                                                         const int* __restrict__ pidx,
                                                         const int* __restrict__ worklist,
                                                         const int* __restrict__ nwork,
                                                         int* __restrict__ best_idx) {
  const int tid = threadIdx.x;
  const int wave = tid >> 6;
  const int lane = tid & 63;
  const int wgid = blockIdx.x * 4 + wave;
  const int wstep = gridDim.x * 4;

  __shared__ float zs[4][D];
  const int n = *nwork;

  for (int j = wgid; j < n; j += wstep) {
    const int row = worklist[j];
    if (lane < 16) ((f32x4*)zs[wave])[lane] = *((const f32x4*)(z_e + (size_t)row * D) + lane);

    float pb[KSPLIT], ps[KSPLIT];
    int pi[KSPLIT];
    float B = __builtin_inff();
#pragma unroll
    for (int h = 0; h < KSPLIT; ++h) {
      size_t o = (size_t)h * 65536 + row;
      pb[h] = pbest[o];
      ps[h] = psec[o];
      pi[h] = pidx[o];
      B = fminf(B, pb[h]);
    }
    const float lim = B + MARGIN;

    float bv = __builtin_inff();
    int bi = 0;
#pragma unroll
    for (int h = 0; h < KSPLIT; ++h) {
      if (ps[h] < lim) {
        // exact fp32 scan of this 1024-code half
        float hb = __builtin_inff();
        int hx = 0;
        for (int t = 0; t < 16; ++t) {
          int c = h * 1024 + t * 64 + lane;
          const f32x4* er = (const f32x4*)(emb + (size_t)c * D);
          f32x4 a = {0.f, 0.f, 0.f, 0.f};
#pragma unroll
          for (int i = 0; i < 16; ++i)
            a = __builtin_elementwise_fma(er[i], ((const f32x4*)zs[wave])[i], a);
          float dot = (a[0] + a[1]) + (a[2] + a[3]);
          float q = fmaf(-2.f, dot, esq[c]);
          if (q < hb) { hb = q; hx = c; }  // ascending t => first occurrence
        }
#pragma unroll
        for (int off = 32; off > 0; off >>= 1) {
          float ov = __shfl_down(hb, off);
          int oi = __shfl_down(hx, off);
          if (ov < hb || (ov == hb && oi < hx)) { hb = ov; hx = oi; }
        }
        hb = __shfl(hb, 0);
        hx = __shfl(hx, 0);
        if (hb < bv || (hb == bv && hx < bi)) { bv = hb; bi = hx; }
      } else if (pb[h] < lim) {
        // single candidate: exact dot for code pi[h]
        int c = pi[h];
        float p = emb[(size_t)c * D + lane] * zs[wave][lane];
#pragma unroll
        for (int off = 1; off < 64; off <<= 1) p += __shfl_xor(p, off);
        float q = fmaf(-2.f, p, esq[c]);
        if (q < bv || (q == bv && c < bi)) { bv = q; bi = c; }
      }
    }
    if (lane == 0) best_idx[row] = bi;
  }
}

// ---------------------------------------------------------------------------
// Gather z_q, write z_q_st + indices, loss partials, histogram.
// ---------------------------------------------------------------------------
__global__ __launch_bounds__(256) void finalize_kernel(const float* __restrict__ z_e,
                                                       const float* __restrict__ emb,
                                                       const int* __restrict__ best_idx,
                                                       float* __restrict__ out_zq,
                                                       float* __restrict__ out_idx,
                                                       int* __restrict__ counts,
                                                       float* __restrict__ block_loss) {
  const int tid = threadIdx.x;
  const int wave = tid >> 6;
  const int lane = tid & 63;
  const int row = blockIdx.x * 4 + wave;

  int bidx = best_idx[row];
  float ze = z_e[(size_t)row * D + lane];
  float zq = emb[(size_t)bidx * D + lane];
  float st = ze + (zq - ze);  // straight-through, same formula as reference
  out_zq[(size_t)row * D + lane] = st;

  float diff = zq - ze;
  float sq = diff * diff;
#pragma unroll
  for (int off = 32; off > 0; off >>= 1) sq += __shfl_down(sq, off);

  __shared__ float ls[4];
  if (lane == 0) {
    ls[wave] = sq;
    out_idx[row] = (float)bidx;
    atomicAdd(&counts[bidx], 1);
  }
  __syncthreads();
  if (tid == 0) block_loss[blockIdx.x] = ls[0] + ls[1] + ls[2] + ls[3];
}

// ---------------------------------------------------------------------------
// Final scalars: commitment loss, perplexity, n_active. Single block.
// ---------------------------------------------------------------------------
__global__ __launch_bounds__(1024) void stats_kernel(const float* __restrict__ block_loss,
                                                     int nblocks,
                                                     const int* __restrict__ counts,
                                                     float* __restrict__ out_scalars,
                                                     int N) {
  const int tid = threadIdx.x;
  const int wave = tid >> 6;
  const int lane = tid & 63;

  float lsum = 0.f;
  for (int i = tid; i < nblocks; i += 1024) lsum += block_loss[i];

  float ent = 0.f;
  int act = 0;
  const float invN = 1.0f / (float)N;
  for (int k = tid; k < K; k += 1024) {
    float p = (float)counts[k] * invN;
    ent += p * logf(p + 1e-10f);
    act += (p > 0.001f) ? 1 : 0;
  }

#pragma unroll
  for (int off = 32; off > 0; off >>= 1) {
    lsum += __shfl_down(lsum, off);
    ent += __shfl_down(ent, off);
    act += __shfl_down(act, off);
  }

  __shared__ float sl[16], se[16];
  __shared__ int sa[16];
  if (lane == 0) { sl[wave] = lsum; se[wave] = ent; sa[wave] = act; }
  __syncthreads();
  if (tid == 0) {
    float L = 0.f, E = 0.f;
    int A = 0;
#pragma unroll
    for (int w = 0; w < 16; ++w) { L += sl[w]; E += se[w]; A += sa[w]; }
    out_scalars[0] = 0.25f * L / ((float)N * (float)D);  // commitment loss
    out_scalars[1] = expf(-E);                            // perplexity
    out_scalars[2] = (float)A;                            // n_active
  }
}

extern "C" void kernel_launch(void* const* d_in, const int* in_sizes, int n_in,
                              void* d_out, int out_size, void* d_ws, size_t ws_size,
                              hipStream_t stream) {
  const float* z_e = (const float*)d_in[0];
  const float* emb = (const float*)d_in[1];
  const int N = in_sizes[0] / D;  // 65536

  float* out = (float*)d_out;
  float* out_zq = out;
  float* out_idx = out + (size_t)N * D;
  float* out_scalars = out + (size_t)N * (D + 1);

  char* ws = (char*)d_ws;
  size_t o = 0;
  int* counts = (int*)(ws + o);      o += 16384;                  // 4096 ints
  int* nwork = (int*)(ws + o);       o += 256;                    // 1 int (+pad)
  float* esq = (float*)(ws + o);     o += 16384;                  // 4096 f32
  short* e_h = (short*)(ws + o);     o += (size_t)K * D * 2;      // 512 KB (fp16)
  o += 4096;                                                      // prefetch pad
  float* pbest = (float*)(ws + o);   o += (size_t)KSPLIT * N * 4; // 1 MB
  float* psec = (float*)(ws + o);    o += (size_t)KSPLIT * N * 4; // 1 MB
  int* pidx = (int*)(ws + o);        o += (size_t)KSPLIT * N * 4; // 1 MB
  int* best_idx = (int*)(ws + o);    o += (size_t)N * 4;          // 256 KB
  int* worklist = (int*)(ws + o);    o += (size_t)N * 4;          // 256 KB
  float* block_loss = (float*)(ws + o);                            // 64 KB

  hipMemsetAsync(counts, 0, 16384 + 256, stream);  // counts + nwork

  esq_kernel<<<K / 256, 256, 0, stream>>>(emb, esq);
  esplit_kernel<<<(K / 16) * 2 * 64 / 256, 256, 0, stream>>>(emb, e_h);
  dist_kernel<<<dim3(N / 128, KSPLIT), 256, 0, stream>>>(z_e, e_h, esq,
                                                         pbest, psec, pidx);
  merge_kernel<<<N / 256, 256, 0, stream>>>(pbest, psec, pidx, best_idx,
                                            worklist, nwork, N);
  resolve_kernel<<<512, 256, 0, stream>>>(z_e, emb, esq, pbest, psec, pidx,
                                          worklist, nwork, best_idx);
  finalize_kernel<<<N / 4, 256, 0, stream>>>(z_e, emb, best_idx, out_zq, out_idx,
                                             counts, block_loss);
  stats_kernel<<<1, 1024, 0, stream>>>(block_loss, N / 4, counts, out_scalars, N);
}